// Round 2
// baseline (145.662 us; speedup 1.0000x reference)
//
#include <hip/hip_runtime.h>
#include <stdint.h>

#define D_K 512
#define C_CLS 85742
#define N_TILES 670            // ceil(85742/128)
#define N_PART (N_TILES * 2)

using bf16x8 = __attribute__((ext_vector_type(8))) short;
using f32x4  = __attribute__((ext_vector_type(4))) float;

__device__ __forceinline__ unsigned short f2bf(float f) {
  unsigned int u = __builtin_bit_cast(unsigned int, f);
  u += 0x7FFFu + ((u >> 16) & 1u);          // round-to-nearest-even
  return (unsigned short)(u >> 16);
}
__device__ __forceinline__ float bf2f(unsigned short h) {
  return __builtin_bit_cast(float, ((unsigned int)h) << 16);
}
__device__ __forceinline__ float sq8(const float4& a, const float4& b) {
  return a.x*a.x + a.y*a.y + a.z*a.z + a.w*a.w +
         b.x*b.x + b.y*b.y + b.z*b.z + b.w*b.w;
}
__device__ __forceinline__ void pack8(const float4& a, const float4& b, unsigned short* h) {
  h[0]=f2bf(a.x); h[1]=f2bf(a.y); h[2]=f2bf(a.z); h[3]=f2bf(a.w);
  h[4]=f2bf(b.x); h[5]=f2bf(b.y); h[6]=f2bf(b.z); h[7]=f2bf(b.w);
}

// ---------------- Pass A: normalize x -> bf16 xn, save ||x|| ----------------
__global__ __launch_bounds__(256) void k_xnorm(const float* __restrict__ X,
                                               unsigned short* __restrict__ XN,
                                               float* __restrict__ FN) {
  int row  = blockIdx.x * 4 + (threadIdx.x >> 6);
  int lane = threadIdx.x & 63;
  const float4* px = (const float4*)(X + (size_t)row * D_K + lane * 8);
  float4 u = px[0], v = px[1];
  float nsq = sq8(u, v);
#pragma unroll
  for (int m = 1; m <= 32; m <<= 1) nsq += __shfl_xor(nsq, m);
  float nrm = sqrtf(nsq);
  float inv = 1.0f / fmaxf(nrm, 1e-12f);
  float4 a = make_float4(u.x*inv, u.y*inv, u.z*inv, u.w*inv);
  float4 b = make_float4(v.x*inv, v.y*inv, v.z*inv, v.w*inv);
  alignas(16) unsigned short h[8];
  pack8(a, b, h);
  *(bf16x8*)(XN + (size_t)row * D_K + lane * 8) = *(const bf16x8*)h;
  if (lane == 0) FN[row] = nrm;
}

// ---- Pass C: 128x128 bf16 MFMA GEMM, double-buffered 2-phase pipeline with
// ----  counted vmcnt barriers. B = raw W fp32 reg-staged -> bf16 LDS (fused
// ----  ||w||^2); A = xn bf16 via global_load_lds. Epilogue: per-(row,64col)
// ----  (max, sumexp) partials of z = clamp(cos)*||x||.
__global__ __launch_bounds__(256) void k_gemm_lse(const float* __restrict__ W,
                                                  const unsigned short* __restrict__ XN,
                                                  const float* __restrict__ FN,
                                                  float2* __restrict__ PART) {
  __shared__ alignas(16) unsigned short As[2][4096];   // [buf][128 rows x 32 cols]
  __shared__ alignas(16) unsigned short Bs[2][4096];
  __shared__ float nsqS[128];
  __shared__ float fnS[128];

  int bid = blockIdx.x;
  // bijective XCD chunking: 2680 = 8*335; 4 m-blocks of an n-tile stay on one XCD
  int wg    = (bid & 7) * 335 + (bid >> 3);
  int ntile = wg >> 2, mtile = wg & 3;
  int m0 = mtile * 128, n0 = ntile * 128;

  int t    = threadIdx.x;
  int lane = t & 63, wid = t >> 6;
  int wm = wid >> 1, wn = wid & 1;
  int s = lane & 15, g = lane >> 4;

  // B staging: thread t owns row t>>1 (clamped -> uniform vmcnt), cols (t&1)*16..+15
  int gr = n0 + (t >> 1); if (gr > C_CLS - 1) gr = C_CLS - 1;
  const float* pB = W + (size_t)gr * D_K + (t & 1) * 16;

  // A staging (global_load_lds 16B): inst i covers rows i*64+(t>>2), col (t&3)*8
  const unsigned short* gA = XN + (size_t)(m0 + (t >> 2)) * D_K + (t & 3) * 8;

  f32x4 acc[4][4] = {};
  float nsq = 0.f;
  float4 rb0, rb1, rb2, rb3;

#define GLDS(srcp, dstp) __builtin_amdgcn_global_load_lds( \
    (const __attribute__((address_space(1))) unsigned int*)(srcp), \
    (__attribute__((address_space(3))) unsigned int*)(dstp), 16, 0, 0)

#define STAGE_A(b, kk) do { \
    GLDS(gA + (size_t)(kk) * 32,             &As[b][wid * 512]); \
    GLDS(gA + 64 * D_K + (size_t)(kk) * 32,  &As[b][2048 + wid * 512]); \
    __builtin_amdgcn_sched_barrier(0); \
  } while (0)

#define PREF_B(kk) do { \
    const float* q_ = pB + (kk) * 32; \
    rb0 = *(const float4*)q_;       rb1 = *(const float4*)(q_ + 4); \
    rb2 = *(const float4*)(q_ + 8); rb3 = *(const float4*)(q_ + 12); \
  } while (0)

#define CONV_B(b) do { \
    nsq += sq8(rb0, rb1) + sq8(rb2, rb3); \
    alignas(16) unsigned short h0_[8], h1_[8]; \
    pack8(rb0, rb1, h0_); pack8(rb2, rb3, h1_); \
    *(bf16x8*)(&Bs[b][(t >> 1) * 32 + (t & 1) * 16])     = *(const bf16x8*)h0_; \
    *(bf16x8*)(&Bs[b][(t >> 1) * 32 + (t & 1) * 16 + 8]) = *(const bf16x8*)h1_; \
  } while (0)

#define FRAGS_MFMA(b) do { \
    bf16x8 af[4], bfr[4]; \
    _Pragma("unroll") for (int mf = 0; mf < 4; ++mf) \
      af[mf] = *(const bf16x8*)(&As[b][(wm * 64 + mf * 16 + s) * 32 + g * 8]); \
    _Pragma("unroll") for (int nf = 0; nf < 4; ++nf) \
      bfr[nf] = *(const bf16x8*)(&Bs[b][(wn * 64 + nf * 16 + s) * 32 + g * 8]); \
    _Pragma("unroll") for (int mf = 0; mf < 4; ++mf) \
      _Pragma("unroll") for (int nf = 0; nf < 4; ++nf) \
        acc[mf][nf] = __builtin_amdgcn_mfma_f32_16x16x32_bf16(af[mf], bfr[nf], acc[mf][nf], 0, 0, 0); \
  } while (0)

  // counted barrier: drains the 2 gloads (oldest), leaves 4 B-prefetch in flight
#define BARC() do { \
    asm volatile("s_waitcnt vmcnt(4) lgkmcnt(0)" ::: "memory"); \
    __builtin_amdgcn_s_barrier(); \
    __builtin_amdgcn_sched_barrier(0); \
  } while (0)
#define BAR0() do { \
    asm volatile("s_waitcnt vmcnt(0) lgkmcnt(0)" ::: "memory"); \
    __builtin_amdgcn_s_barrier(); \
    __builtin_amdgcn_sched_barrier(0); \
  } while (0)

  // prologue: tile 0 into buf0, tile-1 B regs in flight
  PREF_B(0);
  STAGE_A(0, 0);
  CONV_B(0);
  PREF_B(1);
  BARC();

  for (int kt = 0; kt < 14; kt += 2) {
    STAGE_A(1, kt + 1);
    CONV_B(1);                // B(kt+1) -> Bs1
    PREF_B(kt + 2);
    FRAGS_MFMA(0);            // tile kt
    BARC();
    STAGE_A(0, kt + 2);
    CONV_B(0);                // B(kt+2) -> Bs0
    PREF_B(kt + 3);
    FRAGS_MFMA(1);            // tile kt+1
    BARC();
  }
  // kt = 14
  STAGE_A(1, 15);
  CONV_B(1);                  // B(15) -> Bs1
  FRAGS_MFMA(0);              // tile 14
  BAR0();
  // kt = 15
  FRAGS_MFMA(1);              // tile 15

  // finish per-row ||w||^2 (2 col-chunk owners: t, t^1)
  nsq += __shfl_xor(nsq, 1);
  if ((t & 1) == 0) nsqS[t >> 1] = nsq;
  if (t < 128) fnS[t] = FN[m0 + t];
  __syncthreads();

  float rinv[4]; int cvalid[4];
#pragma unroll
  for (int nf = 0; nf < 4; ++nf) {
    int cl = wn * 64 + nf * 16 + s;
    cvalid[nf] = (n0 + cl) < C_CLS;
    rinv[nf] = 1.0f / fmaxf(sqrtf(nsqS[cl]), 1e-12f);
  }
  const float NEG_INF = -__builtin_inff();
#pragma unroll
  for (int mf = 0; mf < 4; ++mf) {
#pragma unroll
    for (int q = 0; q < 4; ++q) {
      int rl = wm * 64 + mf * 16 + g * 4 + q;     // D row = (lane>>4)*4+reg
      float fr = fnS[rl];
      float z[4]; float mx = NEG_INF;
#pragma unroll
      for (int nf = 0; nf < 4; ++nf) {
        float cc = acc[mf][nf][q] * rinv[nf];
        cc = fminf(fmaxf(cc, -1.0f), 1.0f);
        z[nf] = cvalid[nf] ? cc * fr : NEG_INF;
        mx = fmaxf(mx, z[nf]);
      }
#pragma unroll
      for (int d = 1; d <= 8; d <<= 1) mx = fmaxf(mx, __shfl_xor(mx, d));
      float se = 0.f;
#pragma unroll
      for (int nf = 0; nf < 4; ++nf) se += __expf(z[nf] - mx);  // exp(-inf)=0
#pragma unroll
      for (int d = 1; d <= 8; d <<= 1) se += __shfl_xor(se, d);
      if (s == mf * 4 + q)
        PART[(size_t)(m0 + rl) * N_PART + (ntile * 2 + wn)] = make_float2(mx, se);
    }
  }
}

// ------- Pass D: per-row target logit (unmodified + margin-modified) --------
__global__ __launch_bounds__(64) void k_target(const float* __restrict__ W,
                                               const unsigned short* __restrict__ XN,
                                               const float* __restrict__ FN,
                                               const int* __restrict__ LBL,
                                               float2* __restrict__ ZT) {
  int row = blockIdx.x;
  int lane = threadIdx.x;
  int lab = LBL[row];
  const float* pw = W + (size_t)lab * D_K + lane * 8;
  const unsigned short* px = XN + (size_t)row * D_K + lane * 8;
  float dot = 0.f, nsq = 0.f;
#pragma unroll
  for (int j = 0; j < 8; ++j) {
    float w = pw[j];
    nsq += w * w;
    dot += bf2f(px[j]) * bf2f(f2bf(w));   // match GEMM numerics (bf16 operands)
  }
#pragma unroll
  for (int m = 1; m <= 32; m <<= 1) { dot += __shfl_xor(dot, m); nsq += __shfl_xor(nsq, m); }
  if (lane == 0) {
    const float LAMB = 1000.0f / 1.12f;   // iter=1 -> max(5, 1000/1.12)
    float rinv = 1.0f / fmaxf(sqrtf(nsq), 1e-12f);
    float c = fminf(fmaxf(dot * rinv, -1.0f), 1.0f);
    float c2 = c * c;
    float cm = 8.0f * c2 * c2 - 8.0f * c2 + 1.0f;   // cos(4θ)
    float th = acosf(c);
    float kf = floorf(4.0f * th / 3.14159265f);
    float phi = ((((int)kf) & 1) ? -cm : cm) - 2.0f * kf;
    float fr = FN[row];
    float zu = fr * c;
    float zm = fr * (c + (phi - c) / (1.0f + LAMB));
    ZT[row] = make_float2(zu, zm);
  }
}

// ------- Pass E1: combine 1340 partials per row -> per-row CE loss ----------
__global__ __launch_bounds__(256) void k_lse(const float2* __restrict__ PART,
                                             const float2* __restrict__ ZT,
                                             float* __restrict__ LOSSI) {
  int row = blockIdx.x;
  int t = threadIdx.x;
  const float NEG_INF = -__builtin_inff();
  float m = NEG_INF, ss = 0.f;
  for (int p = t; p < N_PART; p += 256) {
    float2 ps = PART[(size_t)row * N_PART + p];
    if (ps.y > 0.f) {
      if (ps.x > m) { ss = ss * __expf(m - ps.x) + ps.y; m = ps.x; }
      else          { ss += ps.y * __expf(ps.x - m); }
    }
  }
  __shared__ float sm[256], sv[256];
  sm[t] = m; sv[t] = ss;
  __syncthreads();
  for (int o = 128; o > 0; o >>= 1) {
    if (t < o) {
      float m1 = sm[t], s1 = sv[t];
      float m2 = sm[t + o], s2 = sv[t + o];
      float mm = fmaxf(m1, m2);
      float e1 = (m1 > NEG_INF) ? s1 * __expf(m1 - mm) : 0.f;
      float e2 = (m2 > NEG_INF) ? s2 * __expf(m2 - mm) : 0.f;
      sm[t] = mm; sv[t] = e1 + e2;
    }
    __syncthreads();
  }
  if (t == 0) {
    float M = sm[0], S = sv[0];
    float2 zt = ZT[row];
    // swap the target's unmodified exp term for the margin-modified one
    S += __expf(zt.y - M) - __expf(zt.x - M);
    LOSSI[row] = M + logf(S) - zt.y;
  }
}

// ------- Pass E2: mean over 512 rows -> scalar loss -------------------------
__global__ __launch_bounds__(256) void k_mean(const float* __restrict__ LOSSI,
                                              float* __restrict__ OUT) {
  int t = threadIdx.x;
  float s_ = LOSSI[t] + LOSSI[t + 256];
#pragma unroll
  for (int m = 1; m <= 32; m <<= 1) s_ += __shfl_xor(s_, m);
  __shared__ float wsum[4];
  if ((t & 63) == 0) wsum[t >> 6] = s_;
  __syncthreads();
  if (t == 0) OUT[0] = (wsum[0] + wsum[1] + wsum[2] + wsum[3]) * (1.0f / 512.0f);
}

extern "C" void kernel_launch(void* const* d_in, const int* in_sizes, int n_in,
                              void* d_out, int out_size, void* d_ws, size_t ws_size,
                              hipStream_t stream) {
  const float* X   = (const float*)d_in[0];   // [512,512] f32
  const float* W   = (const float*)d_in[1];   // [85742,512] f32
  const int*   LBL = (const int*)d_in[2];     // [512] i32
  float* OUT = (float*)d_out;

  char* ws = (char*)d_ws;
  unsigned short* XN = (unsigned short*)ws;            // 512*512*2       = 524288
  float*  FN    = (float*)(ws + 524288);               // 512*4           = 2048
  float2* ZT    = (float2*)(ws + 526336);              // 512*8           = 4096
  float*  LOSSI = (float*)(ws + 530432);               // 512*4           = 2048
  float2* PART  = (float2*)(ws + 532480);              // 512*1340*8      = 5488640

  k_xnorm  <<<dim3(128),  dim3(256), 0, stream>>>(X, XN, FN);
  k_gemm_lse<<<dim3(2680), dim3(256), 0, stream>>>(W, XN, FN, PART);
  k_target <<<dim3(512),  dim3(64),  0, stream>>>(W, XN, FN, LBL, ZT);
  k_lse    <<<dim3(512),  dim3(256), 0, stream>>>(PART, ZT, LOSSI);
  k_mean   <<<dim3(1),    dim3(256), 0, stream>>>(LOSSI, OUT);
}